// Round 3
// baseline (72.490 us; speedup 1.0000x reference)
//
#include <hip/hip_runtime.h>
#include <hip/hip_bf16.h>

// MultiHeadAttentionQuantum — analytic collapse of the quantum layer.
//   q = x@Wq^T + bq ; d_w = cos(q_w + phi_w)
//   CNOT chain parity: out wire 0 = d1*...*d7 ; out wire w>=1 = d0*...*d_w
//   y = p @ Wc^T + bc
// k/v branches are dead code. M = 16*2048 = 32768 tokens, E = 8.
// Inputs float32 (NaN evidence r1), output float32 (reference output dtype; r2
// failure explained by bf16-packing into an f32 buffer).

__global__ __launch_bounds__(256) void mhaq_kernel(
    const float4* __restrict__ x,    // 2 x float4 per token (8 f32 = 32 B)
    const float*  __restrict__ Wq,
    const float*  __restrict__ bq,
    const float*  __restrict__ Wc,
    const float*  __restrict__ bc,
    const float*  __restrict__ phi,
    float4* __restrict__ out, int M)
{
    __shared__ float sWq[64];   // q_w = sum_e x_e * sWq[w*8+e]
    __shared__ float sWc[64];   // y_e = sum_w p_w * sWc[e*8+w]
    __shared__ float sb[8];     // bq + phi folded
    __shared__ float sbc[8];

    const int tid = threadIdx.x;
    if (tid < 64)        sWq[tid]       = Wq[tid];
    else if (tid < 128)  sWc[tid - 64]  = Wc[tid - 64];
    else if (tid < 136)  sb[tid - 128]  = bq[tid - 128] + phi[tid - 128];
    else if (tid < 144)  sbc[tid - 136] = bc[tid - 136];
    __syncthreads();

    const int m = blockIdx.x * 256 + tid;
    if (m >= M) return;

    // token = 32 B: two coalesced dwordx4 loads
    const float4 xa = x[2 * m];
    const float4 xb = x[2 * m + 1];
    const float xv[8] = {xa.x, xa.y, xa.z, xa.w, xb.x, xb.y, xb.z, xb.w};

    // q = x @ Wq^T + (bq + phi);  d = cos(q)
    float d[8];
    #pragma unroll
    for (int w = 0; w < 8; ++w) {
        float qv = sb[w];
        #pragma unroll
        for (int e = 0; e < 8; ++e) qv = fmaf(xv[e], sWq[w * 8 + e], qv);
        d[w] = __cosf(qv);
    }

    // prefix products: p[w>=1] = d0*...*dw ; p[0] = d1*...*d7
    float p[8];
    p[1] = d[0] * d[1];
    #pragma unroll
    for (int w = 2; w < 8; ++w) p[w] = p[w - 1] * d[w];
    p[0] = (d[1] * d[2]) * (d[3] * d[4]) * ((d[5] * d[6]) * d[7]);

    // y = p @ Wc^T + bc, f32 output: two 16 B stores per token
    float y[8];
    #pragma unroll
    for (int e = 0; e < 8; ++e) {
        float ye = sbc[e];
        #pragma unroll
        for (int w = 0; w < 8; ++w) ye = fmaf(p[w], sWc[e * 8 + w], ye);
        y[e] = ye;
    }
    out[2 * m]     = make_float4(y[0], y[1], y[2], y[3]);
    out[2 * m + 1] = make_float4(y[4], y[5], y[6], y[7]);
}

extern "C" void kernel_launch(void* const* d_in, const int* in_sizes, int n_in,
                              void* d_out, int out_size, void* d_ws, size_t ws_size,
                              hipStream_t stream) {
    // setup_inputs order: x, Wq, bq, Wk, bk, Wv, bv, Wc, bc, phi
    const float* x   = (const float*)d_in[0];
    const float* Wq  = (const float*)d_in[1];
    const float* bq  = (const float*)d_in[2];
    const float* Wc  = (const float*)d_in[7];
    const float* bc  = (const float*)d_in[8];
    const float* phi = (const float*)d_in[9];

    const int M = in_sizes[0] / 8;  // 32768 tokens
    const int blocks = (M + 255) / 256;
    mhaq_kernel<<<blocks, 256, 0, stream>>>((const float4*)x, Wq, bq, Wc, bc, phi,
                                            (float4*)d_out, M);
}